// Round 10
// baseline (3003.713 us; speedup 1.0000x reference)
//
#include <hip/hip_runtime.h>
#include <math.h>

#define B_TOT 2048
#define T_LEN 512
#define HDIM 64
#define FC1 50
#define NSUP 514   // 512 + max skew 2

typedef __bf16 bf16x8 __attribute__((ext_vector_type(8)));
typedef float f32x4 __attribute__((ext_vector_type(4)));
typedef unsigned int u32x4 __attribute__((ext_vector_type(4)));

// Fast transcendentals (no -ffast-math in harness; "/" would emit 12-inst IEEE div)
__device__ __forceinline__ float vrcp(float x) {
  float r; asm("v_rcp_f32 %0, %1" : "=v"(r) : "v"(x)); return r;
}
__device__ __forceinline__ float vexp2(float x) {
  float r; asm("v_exp_f32 %0, %1" : "=v"(r) : "v"(x)); return r;
}
__device__ __forceinline__ float sigm(float x) {
  return vrcp(1.0f + vexp2(x * -1.44269504088896340736f));
}
__device__ __forceinline__ float tanh_(float x) {
  return fmaf(2.0f, vrcp(1.0f + vexp2(x * -2.8853900817779268f)), -1.0f);
}

// lgkm-only barrier: LDS visibility without draining global queues.
#define BARRIER() asm volatile("s_waitcnt lgkmcnt(0)\n\ts_barrier" ::: "memory")
#define MFMA __builtin_amdgcn_mfma_f32_16x16x32_bf16

// Planar [16][64] bf16, 16B-chunk XOR swizzle: full-wave b128 = uniform 8 lanes/bank-group.
#define HADDR(row, chunk) (((row) << 6) + ((((chunk) ^ ((row) & 7))) << 3))

__device__ __forceinline__ void unpk(u32x4 p0, u32x4 p1, bf16x8* hi, bf16x8* lo) {
  u32x4 h, l;
  h[0] = __builtin_amdgcn_perm(p0[1], p0[0], 0x05040100u);
  h[1] = __builtin_amdgcn_perm(p0[3], p0[2], 0x05040100u);
  h[2] = __builtin_amdgcn_perm(p1[1], p1[0], 0x05040100u);
  h[3] = __builtin_amdgcn_perm(p1[3], p1[2], 0x05040100u);
  l[0] = __builtin_amdgcn_perm(p0[1], p0[0], 0x07060302u);
  l[1] = __builtin_amdgcn_perm(p0[3], p0[2], 0x07060302u);
  l[2] = __builtin_amdgcn_perm(p1[1], p1[0], 0x07060302u);
  l[3] = __builtin_amdgcn_perm(p1[3], p1[2], 0x07060302u);
  *hi = __builtin_bit_cast(bf16x8, h);
  *lo = __builtin_bit_cast(bf16x8, l);
}

// Intra-block skewed layer pipeline with the R9-verified step.
// Set s (4 waves) = layer BASE+s; at superstep n computes tl = n - s.
// Parity: write planes [s][n&1], read [s][1-(n&1)] (own h(t-1)) and
// [s-1][1-(n&1)] (upstream h_{l-1}(tl), produced at superstep n-1). One
// lgkm barrier per superstep. Numerics bit-identical to R9 (absmax 1.2207e-4).
#define STEPP(N_, P_)                                                          \
  {                                                                            \
    const int tl = (N_) - set;                                                 \
    if (tl >= 0 && tl < T_LEN) {                                               \
      bf16x8 ahh0 = *(const bf16x8*)&Hhi[set][1 - (P_)][HADDR(nn, cg)];        \
      bf16x8 ahh1 = *(const bf16x8*)&Hhi[set][1 - (P_)][HADDR(nn, 4 + cg)];    \
      bf16x8 ahl0 = *(const bf16x8*)&Hlo[set][1 - (P_)][HADDR(nn, cg)];        \
      bf16x8 ahl1 = *(const bf16x8*)&Hlo[set][1 - (P_)][HADDR(nn, 4 + cg)];    \
      f32x4 accs[4];                                                           \
      if (BASE == 0 && set == 0) {                                             \
        _Pragma("unroll") for (int g = 0; g < 4; ++g) {                        \
          f32x4 a;                                                             \
          _Pragma("unroll") for (int r = 0; r < 4; ++r)                        \
            a[r] = bias[g] + xw[g*3+0] * xr[P_][r*3+0]                         \
                           + xw[g*3+1] * xr[P_][r*3+1]                         \
                           + xw[g*3+2] * xr[P_][r*3+2];                        \
          accs[g] = a;                                                         \
        }                                                                      \
      } else {                                                                 \
        bf16x8 xh0, xl0, xh1, xl1;                                             \
        if (IN_GLB && set == 0) {                                              \
          unpk(xpk[P_][0], xpk[P_][1], &xh0, &xl0);                            \
          unpk(xpk[P_][2], xpk[P_][3], &xh1, &xl1);                            \
        } else {                                                               \
          xh0 = *(const bf16x8*)&Hhi[set - 1][1 - (P_)][HADDR(nn, cg)];        \
          xh1 = *(const bf16x8*)&Hhi[set - 1][1 - (P_)][HADDR(nn, 4 + cg)];    \
          xl0 = *(const bf16x8*)&Hlo[set - 1][1 - (P_)][HADDR(nn, cg)];        \
          xl1 = *(const bf16x8*)&Hlo[set - 1][1 - (P_)][HADDR(nn, 4 + cg)];    \
        }                                                                      \
        _Pragma("unroll") for (int g = 0; g < 4; ++g) {                        \
          f32x4 a = {bias[g], bias[g], bias[g], bias[g]};                      \
          a = MFMA(xh0, bih[g][0], a, 0, 0, 0);                                \
          a = MFMA(xh1, bih[g][1], a, 0, 0, 0);                                \
          a = MFMA(xl0, bih[g][0], a, 0, 0, 0);                                \
          a = MFMA(xl1, bih[g][1], a, 0, 0, 0);                                \
          accs[g] = a;                                                         \
        }                                                                      \
      }                                                                        \
      _Pragma("unroll") for (int g = 0; g < 4; ++g) {                          \
        accs[g] = MFMA(ahh0, bhh[g][0], accs[g], 0, 0, 0);                     \
        accs[g] = MFMA(ahh1, bhh[g][1], accs[g], 0, 0, 0);                     \
        accs[g] = MFMA(ahl0, bhh[g][0], accs[g], 0, 0, 0);                     \
        accs[g] = MFMA(ahl1, bhh[g][1], accs[g], 0, 0, 0);                     \
      }                                                                        \
      _Pragma("unroll") for (int r = 0; r < 4; ++r) {                          \
        float iv = sigm(accs[0][r]);                                           \
        float fv = sigm(accs[1][r]);                                           \
        float gv = tanh_(accs[2][r]);                                          \
        float ov = sigm(accs[3][r]);                                           \
        cell[r] = fv * cell[r] + iv * gv;                                      \
        float hv = ov * tanh_(cell[r]);                                        \
        __bf16 h1 = (__bf16)hv;                                                \
        __bf16 h2 = (__bf16)(hv - (float)h1);                                  \
        int mrow = 4 * cg + r;                                                 \
        int ha = HADDR(mrow, uu >> 3) + (uu & 7);                              \
        Hhi[set][P_][ha] = h1;                                                 \
        Hlo[set][P_][ha] = h2;                                                 \
        if (OUT_GLB && set == NSETS - 1) {                                     \
          unsigned int hb = (unsigned int)__builtin_bit_cast(unsigned short, h1) \
                          | ((unsigned int)__builtin_bit_cast(unsigned short, h2) << 16); \
          seqp[((size_t)(bbase + mrow) * T_LEN + tl) * HDIM + uu] = hb;        \
        }                                                                      \
        if (!OUT_GLB && set == NSETS - 1 && tl == T_LEN - 1)                   \
          ((float*)seqp)[(size_t)(bbase + mrow) * T_LEN * HDIM + uu] =         \
              (float)h1 + (float)h2;                                           \
      }                                                                        \
      if (BASE == 0 && set == 0) {                                             \
        int tp = tl + 2; if (tp > T_LEN - 1) tp = T_LEN - 1;                   \
        _Pragma("unroll") for (int r = 0; r < 4; ++r)                          \
          _Pragma("unroll") for (int i = 0; i < 3; ++i)                        \
            xr[P_][r*3+i] = x_f32[((size_t)(bbase + 4*cg + r) * T_LEN + tp) * 3 + i]; \
      }                                                                        \
      if (IN_GLB && set == 0) {                                                \
        int tp = tl + 2; if (tp > T_LEN - 1) tp = T_LEN - 1;                   \
        const unsigned int* px = seqp + xrow + (size_t)tp * HDIM;              \
        xpk[P_][0] = *(const u32x4*)(px + 8 * cg);                             \
        xpk[P_][1] = *(const u32x4*)(px + 8 * cg + 4);                         \
        xpk[P_][2] = *(const u32x4*)(px + 32 + 8 * cg);                        \
        xpk[P_][3] = *(const u32x4*)(px + 32 + 8 * cg + 4);                    \
      }                                                                        \
    }                                                                          \
    BARRIER();                                                                 \
  }

// Kernel A: BASE=0, NSETS=3 (layers 0-2), OUT_GLB -> packed h2 seq.
// Kernel B: BASE=3, NSETS=2 (layers 3-4), IN_GLB <- seq, writes hT f32
//           into seqp[b][0][:] (set0's reads of that region all precede it).
template<int BASE, int NSETS, bool IN_GLB, bool OUT_GLB>
__global__ __launch_bounds__(NSETS * 256, NSETS)
void lstm_pipe2(const float* __restrict__ x_f32,
                const float* __restrict__ w_ih0,
                const float* __restrict__ w_ih_rest,
                const float* __restrict__ w_hh,
                const float* __restrict__ b_ih,
                const float* __restrict__ b_hh,
                unsigned int* __restrict__ seqp)
{
  const int tid  = threadIdx.x;
  const int lane = tid & 63;
  const int wv   = tid >> 6;
  const int set  = wv >> 2;       // layer-set (wave-uniform)
  const int wq   = wv & 3;        // 16-unit column block
  const int nn   = lane & 15;     // batch row (A) / gate col (B/D)
  const int cg   = lane >> 4;     // k-group / D row group
  const int bbase = blockIdx.x * 16;
  const int grow = 16 * wq + nn;
  const int uu   = grow;
  const int layer = BASE + set;

  __shared__ __align__(16) __bf16 Hhi[NSETS][2][1024];  // planar hi, swizzled
  __shared__ __align__(16) __bf16 Hlo[NSETS][2][1024];  // planar lo

  // ---- weights (bf16 B-frags in VGPRs) ----
  bf16x8 bhh[4][2];
#pragma unroll
  for (int g = 0; g < 4; ++g)
#pragma unroll
    for (int kk = 0; kk < 2; ++kk) {
      const float* wp = w_hh + (size_t)layer * 256 * 64
                      + (size_t)(64 * g + grow) * 64 + kk * 32 + 8 * cg;
      bf16x8 t;
#pragma unroll
      for (int e = 0; e < 8; ++e) t[e] = (__bf16)wp[e];
      bhh[g][kk] = t;
    }
  bf16x8 bih[4][2];
  float xw[12];
  if (BASE == 0 && set == 0) {
#pragma unroll
    for (int g = 0; g < 4; ++g)
#pragma unroll
      for (int i = 0; i < 3; ++i) xw[g * 3 + i] = w_ih0[(64 * g + grow) * 3 + i];
  } else {
    const float* wih_l = w_ih_rest + (size_t)(layer - 1) * 256 * 64;
#pragma unroll
    for (int g = 0; g < 4; ++g)
#pragma unroll
      for (int kk = 0; kk < 2; ++kk) {
        const float* wp = wih_l + (size_t)(64 * g + grow) * 64 + kk * 32 + 8 * cg;
        bf16x8 t;
#pragma unroll
        for (int e = 0; e < 8; ++e) t[e] = (__bf16)wp[e];
        bih[g][kk] = t;
      }
  }
  float bias[4];
#pragma unroll
  for (int g = 0; g < 4; ++g) {
    int row = layer * 256 + 64 * g + grow;
    bias[g] = b_ih[row] + b_hh[row];
  }

  // zero all planes, both parities (h(-1) = 0 for every layer-set)
  for (int q = tid; q < NSETS * 2048; q += NSETS * 256) {
    ((__bf16*)Hhi)[q] = (__bf16)0.f;
    ((__bf16*)Hlo)[q] = (__bf16)0.f;
  }

  float cell[4] = {0.f, 0.f, 0.f, 0.f};
  const size_t xrow = (size_t)(bbase + nn) * T_LEN * HDIM;

  float xr[2][12];     // layer-0 x queue (kernel A set0 only)
  u32x4 xpk[2][4];     // packed-seq queue (kernel B set0 only)
  if (BASE == 0 && set == 0) {
#pragma unroll
    for (int p = 0; p < 2; ++p)
#pragma unroll
      for (int r = 0; r < 4; ++r)
#pragma unroll
        for (int i = 0; i < 3; ++i)
          xr[p][r * 3 + i] = x_f32[((size_t)(bbase + 4 * cg + r) * T_LEN + p) * 3 + i];
  }
  if (IN_GLB && set == 0) {
#pragma unroll
    for (int p = 0; p < 2; ++p) {
      const unsigned int* px = seqp + xrow + (size_t)p * HDIM;
      xpk[p][0] = *(const u32x4*)(px + 8 * cg);
      xpk[p][1] = *(const u32x4*)(px + 8 * cg + 4);
      xpk[p][2] = *(const u32x4*)(px + 32 + 8 * cg);
      xpk[p][3] = *(const u32x4*)(px + 32 + 8 * cg + 4);
    }
  }
  __syncthreads();

  for (int n = 0; n < NSUP; n += 2) {
    STEPP(n,     0);
    STEPP(n + 1, 1);
  }
}

// FC head: out[b] = fc2_b + fc2_w . relu(fc1_b + fc1_w . hT[b]);
// hT (f32) lives at seqp[b][0][:].
__global__ __launch_bounds__(256, 1)
void fc_head(const unsigned int* __restrict__ seqp,
             const float* __restrict__ fc1_w, const float* __restrict__ fc1_b,
             const float* __restrict__ fc2_w, const float* __restrict__ fc2_b,
             float* __restrict__ out)
{
    __shared__ float w1[FC1 * HDIM];
    __shared__ float b1[FC1];
    __shared__ float w2[FC1];
    const int tid = threadIdx.x;
    for (int i = tid; i < FC1 * HDIM; i += 256) w1[i] = fc1_w[i];
    if (tid < FC1) { b1[tid] = fc1_b[tid]; w2[tid] = fc2_w[tid]; }
    __syncthreads();

    const int b = blockIdx.x * 256 + tid;
    const float* hT = (const float*)seqp;
    float h[HDIM];
#pragma unroll
    for (int q = 0; q < HDIM; ++q) h[q] = hT[(size_t)b * T_LEN * HDIM + q];
    float acc2 = fc2_b[0];
    for (int m = 0; m < FC1; ++m) {
      float a = b1[m];
#pragma unroll
      for (int q = 0; q < HDIM; ++q) a += w1[m * HDIM + q] * h[q];
      acc2 += w2[m] * fmaxf(a, 0.0f);
    }
    out[b] = acc2;
}

extern "C" void kernel_launch(void* const* d_in, const int* in_sizes, int n_in,
                              void* d_out, int out_size, void* d_ws, size_t ws_size,
                              hipStream_t stream) {
    const float* x         = (const float*)d_in[0];
    const float* w_ih0     = (const float*)d_in[1];
    const float* w_ih_rest = (const float*)d_in[2];
    const float* w_hh      = (const float*)d_in[3];
    const float* b_ih      = (const float*)d_in[4];
    const float* b_hh      = (const float*)d_in[5];
    const float* fc1_w     = (const float*)d_in[6];
    const float* fc1_b     = (const float*)d_in[7];
    const float* fc2_w     = (const float*)d_in[8];
    const float* fc2_b     = (const float*)d_in[9];
    float* out = (float*)d_out;

    unsigned int* seqp = (unsigned int*)d_ws;   // [B,T,64] packed h2 = 256 MiB

    // layers 0-2 pipelined in-block; writes packed layer-2 seq
    lstm_pipe2<0, 3, false, true><<<dim3(B_TOT / 16), dim3(768), 0, stream>>>(
        x, w_ih0, w_ih_rest, w_hh, b_ih, b_hh, seqp);
    // layers 3-4 pipelined; reads seq, writes hT f32 into seqp[:,0,:]
    lstm_pipe2<3, 2, true, false><<<dim3(B_TOT / 16), dim3(512), 0, stream>>>(
        x, w_ih0, w_ih_rest, w_hh, b_ih, b_hh, seqp);
    fc_head<<<dim3(B_TOT / 256), dim3(256), 0, stream>>>(
        seqp, fc1_w, fc1_b, fc2_w, fc2_b, out);
}

// Round 11
// 1694.422 us; speedup vs baseline: 1.7727x; 1.7727x over previous
//
#include <hip/hip_runtime.h>
#include <math.h>

#define B_TOT 2048
#define T_LEN 512
#define HDIM 64
#define FC1 50
#define NSUP 514   // pair kernels: 512 + skew 1, padded even

typedef __bf16 bf16x8 __attribute__((ext_vector_type(8)));
typedef float f32x4 __attribute__((ext_vector_type(4)));
typedef unsigned int u32x4 __attribute__((ext_vector_type(4)));

// Fast transcendentals (no -ffast-math in harness; "/" would emit 12-inst IEEE div)
__device__ __forceinline__ float vrcp(float x) {
  float r; asm("v_rcp_f32 %0, %1" : "=v"(r) : "v"(x)); return r;
}
__device__ __forceinline__ float vexp2(float x) {
  float r; asm("v_exp_f32 %0, %1" : "=v"(r) : "v"(x)); return r;
}
__device__ __forceinline__ float sigm(float x) {
  return vrcp(1.0f + vexp2(x * -1.44269504088896340736f));
}
__device__ __forceinline__ float tanh_(float x) {
  return fmaf(2.0f, vrcp(1.0f + vexp2(x * -2.8853900817779268f)), -1.0f);
}

// lgkm-only barrier: LDS visibility without draining global queues.
#define BARRIER() asm volatile("s_waitcnt lgkmcnt(0)\n\ts_barrier" ::: "memory")
#define MFMA __builtin_amdgcn_mfma_f32_16x16x32_bf16

// Planar [16][64] bf16, 16B-chunk XOR swizzle: full-wave b128 = uniform 8 lanes/bank-group.
#define HADDR(row, chunk) (((row) << 6) + ((((chunk) ^ ((row) & 7))) << 3))

__device__ __forceinline__ void unpk(u32x4 p0, u32x4 p1, bf16x8* hi, bf16x8* lo) {
  u32x4 h, l;
  h[0] = __builtin_amdgcn_perm(p0[1], p0[0], 0x05040100u);
  h[1] = __builtin_amdgcn_perm(p0[3], p0[2], 0x05040100u);
  h[2] = __builtin_amdgcn_perm(p1[1], p1[0], 0x05040100u);
  h[3] = __builtin_amdgcn_perm(p1[3], p1[2], 0x05040100u);
  l[0] = __builtin_amdgcn_perm(p0[1], p0[0], 0x07060302u);
  l[1] = __builtin_amdgcn_perm(p0[3], p0[2], 0x07060302u);
  l[2] = __builtin_amdgcn_perm(p1[1], p1[0], 0x07060302u);
  l[3] = __builtin_amdgcn_perm(p1[3], p1[2], 0x07060302u);
  *hi = __builtin_bit_cast(bf16x8, h);
  *lo = __builtin_bit_cast(bf16x8, l);
}

// ---------------- Pair kernel: 2 layer-sets pipelined in one block ----------
// Empirically (R10-B): 2-set skew pipeline runs a superstep in ~= one layer's
// step time => ~2x layer throughput. 3-set collapses (R7/R10) -- do not fuse 3.
// Set s (4 waves) = layer L0+s; superstep n computes tl = n - s. h handoff via
// planar LDS planes, parity P_ = n&1: write [s][P_], read own h(t-1) and
// upstream h_{l-1}(tl) from [.][1-P_]. One lgkm barrier per superstep.
// Numerics bit-identical to R9 (absmax 1.2207e-4).
#define STEPP(N_, P_)                                                          \
  {                                                                            \
    const int tl = (N_) - set;                                                 \
    if (tl >= 0 && tl < T_LEN) {                                               \
      bf16x8 ahh0 = *(const bf16x8*)&Hhi[set][1 - (P_)][HADDR(nn, cg)];        \
      bf16x8 ahh1 = *(const bf16x8*)&Hhi[set][1 - (P_)][HADDR(nn, 4 + cg)];    \
      bf16x8 ahl0 = *(const bf16x8*)&Hlo[set][1 - (P_)][HADDR(nn, cg)];        \
      bf16x8 ahl1 = *(const bf16x8*)&Hlo[set][1 - (P_)][HADDR(nn, 4 + cg)];    \
      f32x4 accs[4];                                                           \
      if (XIN && set == 0) {                                                   \
        _Pragma("unroll") for (int g = 0; g < 4; ++g) {                        \
          f32x4 a;                                                             \
          _Pragma("unroll") for (int r = 0; r < 4; ++r)                        \
            a[r] = bias[g] + xw[g*3+0] * xr[P_][r*3+0]                         \
                           + xw[g*3+1] * xr[P_][r*3+1]                         \
                           + xw[g*3+2] * xr[P_][r*3+2];                        \
          accs[g] = a;                                                         \
        }                                                                      \
      } else {                                                                 \
        bf16x8 xh0, xl0, xh1, xl1;                                             \
        if (GIN && set == 0) {                                                 \
          unpk(xpk[P_][0], xpk[P_][1], &xh0, &xl0);                            \
          unpk(xpk[P_][2], xpk[P_][3], &xh1, &xl1);                            \
        } else {                                                               \
          xh0 = *(const bf16x8*)&Hhi[0][1 - (P_)][HADDR(nn, cg)];              \
          xh1 = *(const bf16x8*)&Hhi[0][1 - (P_)][HADDR(nn, 4 + cg)];          \
          xl0 = *(const bf16x8*)&Hlo[0][1 - (P_)][HADDR(nn, cg)];              \
          xl1 = *(const bf16x8*)&Hlo[0][1 - (P_)][HADDR(nn, 4 + cg)];          \
        }                                                                      \
        _Pragma("unroll") for (int g = 0; g < 4; ++g) {                        \
          f32x4 a = {bias[g], bias[g], bias[g], bias[g]};                      \
          a = MFMA(xh0, bih[g][0], a, 0, 0, 0);                                \
          a = MFMA(xh1, bih[g][1], a, 0, 0, 0);                                \
          a = MFMA(xl0, bih[g][0], a, 0, 0, 0);                                \
          a = MFMA(xl1, bih[g][1], a, 0, 0, 0);                                \
          accs[g] = a;                                                         \
        }                                                                      \
      }                                                                        \
      _Pragma("unroll") for (int g = 0; g < 4; ++g) {                          \
        accs[g] = MFMA(ahh0, bhh[g][0], accs[g], 0, 0, 0);                     \
        accs[g] = MFMA(ahh1, bhh[g][1], accs[g], 0, 0, 0);                     \
        accs[g] = MFMA(ahl0, bhh[g][0], accs[g], 0, 0, 0);                     \
        accs[g] = MFMA(ahl1, bhh[g][1], accs[g], 0, 0, 0);                     \
      }                                                                        \
      _Pragma("unroll") for (int r = 0; r < 4; ++r) {                          \
        float iv = sigm(accs[0][r]);                                           \
        float fv = sigm(accs[1][r]);                                           \
        float gv = tanh_(accs[2][r]);                                          \
        float ov = sigm(accs[3][r]);                                           \
        cell[r] = fv * cell[r] + iv * gv;                                      \
        float hv = ov * tanh_(cell[r]);                                        \
        __bf16 h1 = (__bf16)hv;                                                \
        __bf16 h2 = (__bf16)(hv - (float)h1);                                  \
        int mrow = 4 * cg + r;                                                 \
        int ha = HADDR(mrow, uu >> 3) + (uu & 7);                              \
        Hhi[set][P_][ha] = h1;                                                 \
        Hlo[set][P_][ha] = h2;                                                 \
        if (set == 1) {                                                        \
          unsigned int hb = (unsigned int)__builtin_bit_cast(unsigned short, h1) \
                          | ((unsigned int)__builtin_bit_cast(unsigned short, h2) << 16); \
          seqp[((size_t)(bbase + mrow) * T_LEN + tl) * HDIM + uu] = hb;        \
        }                                                                      \
      }                                                                        \
      if (XIN && set == 0) {                                                   \
        int tp = tl + 2; if (tp > T_LEN - 1) tp = T_LEN - 1;                   \
        _Pragma("unroll") for (int r = 0; r < 4; ++r)                          \
          _Pragma("unroll") for (int i = 0; i < 3; ++i)                        \
            xr[P_][r*3+i] = x_f32[((size_t)(bbase + 4*cg + r) * T_LEN + tp) * 3 + i]; \
      }                                                                        \
      if (GIN && set == 0) {                                                   \
        int tp = tl + 2; if (tp > T_LEN - 1) tp = T_LEN - 1;                   \
        const unsigned int* px = seqp + xrow + (size_t)tp * HDIM;              \
        xpk[P_][0] = *(const u32x4*)(px + 8 * cg);                             \
        xpk[P_][1] = *(const u32x4*)(px + 8 * cg + 4);                         \
        xpk[P_][2] = *(const u32x4*)(px + 32 + 8 * cg);                        \
        xpk[P_][3] = *(const u32x4*)(px + 32 + 8 * cg + 4);                    \
      }                                                                        \
    }                                                                          \
    BARRIER();                                                                 \
  }

// L0: first layer of the pair. XIN: set0 reads raw x [B,T,3]. GIN: set0 reads
// packed seq from global (prefetch depth 2). set1 always stores packed seq.
// In-place safety (GIN): set0 reads t+2, set1 writes t-1 -> gap 3, rows private.
template<int L0, bool XIN, bool GIN>
__global__ __launch_bounds__(512, 2)
void lstm_pair(const float* __restrict__ x_f32,
               const float* __restrict__ w_ih0,
               const float* __restrict__ w_ih_rest,
               const float* __restrict__ w_hh,
               const float* __restrict__ b_ih,
               const float* __restrict__ b_hh,
               unsigned int* __restrict__ seqp)
{
  const int tid  = threadIdx.x;
  const int lane = tid & 63;
  const int wv   = tid >> 6;
  const int set  = wv >> 2;       // 0 or 1 (wave-uniform)
  const int wq   = wv & 3;
  const int nn   = lane & 15;
  const int cg   = lane >> 4;
  const int bbase = blockIdx.x * 16;
  const int grow = 16 * wq + nn;
  const int uu   = grow;
  const int layer = L0 + set;

  __shared__ __align__(16) __bf16 Hhi[2][2][1024];  // 8 KB
  __shared__ __align__(16) __bf16 Hlo[2][2][1024];  // 8 KB

  bf16x8 bhh[4][2];
#pragma unroll
  for (int g = 0; g < 4; ++g)
#pragma unroll
    for (int kk = 0; kk < 2; ++kk) {
      const float* wp = w_hh + (size_t)layer * 256 * 64
                      + (size_t)(64 * g + grow) * 64 + kk * 32 + 8 * cg;
      bf16x8 t;
#pragma unroll
      for (int e = 0; e < 8; ++e) t[e] = (__bf16)wp[e];
      bhh[g][kk] = t;
    }
  bf16x8 bih[4][2];
  float xw[12];
  if (XIN && set == 0) {
#pragma unroll
    for (int g = 0; g < 4; ++g)
#pragma unroll
      for (int i = 0; i < 3; ++i) xw[g * 3 + i] = w_ih0[(64 * g + grow) * 3 + i];
  } else {
    const float* wih_l = w_ih_rest + (size_t)(layer - 1) * 256 * 64;
#pragma unroll
    for (int g = 0; g < 4; ++g)
#pragma unroll
      for (int kk = 0; kk < 2; ++kk) {
        const float* wp = wih_l + (size_t)(64 * g + grow) * 64 + kk * 32 + 8 * cg;
        bf16x8 t;
#pragma unroll
        for (int e = 0; e < 8; ++e) t[e] = (__bf16)wp[e];
        bih[g][kk] = t;
      }
  }
  float bias[4];
#pragma unroll
  for (int g = 0; g < 4; ++g) {
    int row = layer * 256 + 64 * g + grow;
    bias[g] = b_ih[row] + b_hh[row];
  }

  for (int q = tid; q < 4 * 1024; q += 512) {
    ((__bf16*)Hhi)[q] = (__bf16)0.f;
    ((__bf16*)Hlo)[q] = (__bf16)0.f;
  }

  float cell[4] = {0.f, 0.f, 0.f, 0.f};
  const size_t xrow = (size_t)(bbase + nn) * T_LEN * HDIM;

  float xr[2][12];
  u32x4 xpk[2][4];
  if (XIN && set == 0) {
#pragma unroll
    for (int p = 0; p < 2; ++p)
#pragma unroll
      for (int r = 0; r < 4; ++r)
#pragma unroll
        for (int i = 0; i < 3; ++i)
          xr[p][r * 3 + i] = x_f32[((size_t)(bbase + 4 * cg + r) * T_LEN + p) * 3 + i];
  }
  if (GIN && set == 0) {
#pragma unroll
    for (int p = 0; p < 2; ++p) {
      const unsigned int* px = seqp + xrow + (size_t)p * HDIM;
      xpk[p][0] = *(const u32x4*)(px + 8 * cg);
      xpk[p][1] = *(const u32x4*)(px + 8 * cg + 4);
      xpk[p][2] = *(const u32x4*)(px + 32 + 8 * cg);
      xpk[p][3] = *(const u32x4*)(px + 32 + 8 * cg + 4);
    }
  }
  __syncthreads();

  for (int n = 0; n < NSUP; n += 2) {
    STEPP(n,     0);
    STEPP(n + 1, 1);
  }
}

// -------------- Single-layer kernel (R9, proven 447us/layer) ---------------
#define STEP(T0, P)                                                            \
  {                                                                            \
    if (isA) {                                                                 \
      bf16x8 ahh0 = *(const bf16x8*)&h_hi[P][HADDR(nn, cg)];                   \
      bf16x8 ahh1 = *(const bf16x8*)&h_hi[P][HADDR(nn, 4 + cg)];               \
      bf16x8 ahl0 = *(const bf16x8*)&h_lo[P][HADDR(nn, cg)];                   \
      bf16x8 ahl1 = *(const bf16x8*)&h_lo[P][HADDR(nn, 4 + cg)];               \
      f32x4 accs[4];                                                           \
      _Pragma("unroll")                                                        \
      for (int g = 0; g < 4; ++g) {                                            \
        f32x4 a = accx[P][g][wq * 64 + lane];                                  \
        a = MFMA(ahh0, bhh[g][0], a, 0, 0, 0);                                 \
        a = MFMA(ahh1, bhh[g][1], a, 0, 0, 0);                                 \
        a = MFMA(ahl0, bhh[g][0], a, 0, 0, 0);                                 \
        a = MFMA(ahl1, bhh[g][1], a, 0, 0, 0);                                 \
        accs[g] = a;                                                           \
      }                                                                        \
      _Pragma("unroll")                                                        \
      for (int r = 0; r < 4; ++r) {                                            \
        float iv = sigm(accs[0][r]);                                           \
        float fv = sigm(accs[1][r]);                                           \
        float gv = tanh_(accs[2][r]);                                          \
        float ov = sigm(accs[3][r]);                                           \
        cell[r] = fv * cell[r] + iv * gv;                                      \
        float hv = ov * tanh_(cell[r]);                                        \
        __bf16 h1 = (__bf16)hv;                                                \
        __bf16 h2 = (__bf16)(hv - (float)h1);                                  \
        int mrow = 4 * cg + r;                                                 \
        int ha = HADDR(mrow, uu >> 3) + (uu & 7);                              \
        h_hi[1 - (P)][ha] = h1;                                                \
        h_lo[1 - (P)][ha] = h2;                                                \
      }                                                                        \
    } else {                                                                   \
      if ((T0) > 0) {                                                          \
        _Pragma("unroll")                                                      \
        for (int r = 0; r < 4; ++r) {                                          \
          int mrow = 4 * cg + r;                                               \
          int ha = HADDR(mrow, uu >> 3) + (uu & 7);                            \
          unsigned int hb =                                                    \
              (unsigned int)__builtin_bit_cast(unsigned short, h_hi[P][ha])    \
            | ((unsigned int)__builtin_bit_cast(unsigned short, h_lo[P][ha]) << 16); \
          seqp[((size_t)(bbase + mrow) * T_LEN + (T0) - 1) * HDIM + uu] = hb;  \
        }                                                                      \
      }                                                                        \
      if ((T0) + 1 < T_LEN) {                                                  \
        bf16x8 xh0, xl0, xh1, xl1;                                             \
        unpk(xpk[P][0], xpk[P][1], &xh0, &xl0);                                \
        unpk(xpk[P][2], xpk[P][3], &xh1, &xl1);                                \
        _Pragma("unroll")                                                      \
        for (int g = 0; g < 4; ++g) {                                          \
          f32x4 a = {bias[g], bias[g], bias[g], bias[g]};                      \
          a = MFMA(xh0, bih[g][0], a, 0, 0, 0);                                \
          a = MFMA(xh1, bih[g][1], a, 0, 0, 0);                                \
          a = MFMA(xl0, bih[g][0], a, 0, 0, 0);                                \
          a = MFMA(xl1, bih[g][1], a, 0, 0, 0);                                \
          accx[1 - (P)][g][wq * 64 + lane] = a;                                \
        }                                                                      \
      }                                                                        \
      {                                                                        \
        int tp = (T0) + 3; if (tp >= T_LEN) tp = T_LEN - 1;                    \
        const unsigned int* px = seqp + xrow + (size_t)tp * HDIM;              \
        xpk[P][0] = *(const u32x4*)(px + 8 * cg);                              \
        xpk[P][1] = *(const u32x4*)(px + 8 * cg + 4);                          \
        xpk[P][2] = *(const u32x4*)(px + 32 + 8 * cg);                         \
        xpk[P][3] = *(const u32x4*)(px + 32 + 8 * cg + 4);                     \
      }                                                                        \
    }                                                                          \
    BARRIER();                                                                 \
  }

__global__ __launch_bounds__(512, 2)
void lstm_single(const float* __restrict__ w_ih,   // [256,64]
                 const float* __restrict__ w_hh,   // [256,64]
                 const float* __restrict__ b_ih,
                 const float* __restrict__ b_hh,
                 unsigned int* seqp)
{
    const int tid  = threadIdx.x;
    const int lane = tid & 63;
    const int wv   = tid >> 6;
    const bool isA = (wv < 4);
    const int wq   = wv & 3;
    const int nn   = lane & 15;
    const int cg   = lane >> 4;
    const int bbase = blockIdx.x * 16;
    const int grow = 16 * wq + nn;
    const int uu   = grow;

    __shared__ __align__(16) __bf16 h_hi[2][16 * 64];
    __shared__ __align__(16) __bf16 h_lo[2][16 * 64];
    __shared__ __align__(16) f32x4 accx[2][4][256];

    bf16x8 bhh[4][2];
    bf16x8 bih[4][2];
    float bias[4];
    if (isA) {
#pragma unroll
      for (int g = 0; g < 4; ++g)
#pragma unroll
        for (int kk = 0; kk < 2; ++kk) {
          const float* wp = w_hh + (size_t)(64 * g + grow) * 64 + kk * 32 + 8 * cg;
          bf16x8 t;
#pragma unroll
          for (int e = 0; e < 8; ++e) t[e] = (__bf16)wp[e];
          bhh[g][kk] = t;
        }
    } else {
#pragma unroll
      for (int g = 0; g < 4; ++g) {
        int row = 64 * g + grow;
        bias[g] = b_ih[row] + b_hh[row];
      }
#pragma unroll
      for (int g = 0; g < 4; ++g)
#pragma unroll
        for (int kk = 0; kk < 2; ++kk) {
          const float* wp = w_ih + (size_t)(64 * g + grow) * 64 + kk * 32 + 8 * cg;
          bf16x8 t;
#pragma unroll
          for (int e = 0; e < 8; ++e) t[e] = (__bf16)wp[e];
          bih[g][kk] = t;
        }
    }

    for (int q = tid; q < 1024; q += 512) {
      h_hi[0][q] = (__bf16)0.f; h_hi[1][q] = (__bf16)0.f;
      h_lo[0][q] = (__bf16)0.f; h_lo[1][q] = (__bf16)0.f;
    }

    float cell[4] = {0.f, 0.f, 0.f, 0.f};
    const size_t xrow = (size_t)(bbase + nn) * T_LEN * HDIM;
    u32x4 xpk[2][4];

    if (!isA) {
      const unsigned int* px = seqp + xrow;
      u32x4 q0 = *(const u32x4*)(px + 8 * cg);
      u32x4 q1 = *(const u32x4*)(px + 8 * cg + 4);
      u32x4 q2 = *(const u32x4*)(px + 32 + 8 * cg);
      u32x4 q3 = *(const u32x4*)(px + 32 + 8 * cg + 4);
      bf16x8 xh0, xl0, xh1, xl1;
      unpk(q0, q1, &xh0, &xl0);
      unpk(q2, q3, &xh1, &xl1);
#pragma unroll
      for (int g = 0; g < 4; ++g) {
        f32x4 a = {bias[g], bias[g], bias[g], bias[g]};
        a = MFMA(xh0, bih[g][0], a, 0, 0, 0);
        a = MFMA(xh1, bih[g][1], a, 0, 0, 0);
        a = MFMA(xl0, bih[g][0], a, 0, 0, 0);
        a = MFMA(xl1, bih[g][1], a, 0, 0, 0);
        accx[0][g][wq * 64 + lane] = a;
      }
#pragma unroll
      for (int p = 0; p < 2; ++p) {
        const unsigned int* pq = seqp + xrow + (size_t)(p + 1) * HDIM;
        xpk[p][0] = *(const u32x4*)(pq + 8 * cg);
        xpk[p][1] = *(const u32x4*)(pq + 8 * cg + 4);
        xpk[p][2] = *(const u32x4*)(pq + 32 + 8 * cg);
        xpk[p][3] = *(const u32x4*)(pq + 32 + 8 * cg + 4);
      }
    }
    __syncthreads();

    if (isA) __builtin_amdgcn_s_setprio(1);
    for (int t = 0; t < T_LEN; t += 2) {
      STEP(t, 0);
      STEP(t + 1, 1);
    }
    if (isA) __builtin_amdgcn_s_setprio(0);

    if (!isA) {
#pragma unroll
      for (int r = 0; r < 4; ++r) {
        int mrow = 4 * cg + r;
        int ha = HADDR(mrow, uu >> 3) + (uu & 7);
        unsigned int hb =
            (unsigned int)__builtin_bit_cast(unsigned short, h_hi[0][ha])
          | ((unsigned int)__builtin_bit_cast(unsigned short, h_lo[0][ha]) << 16);
        seqp[((size_t)(bbase + mrow) * T_LEN + (T_LEN - 1)) * HDIM + uu] = hb;
      }
    }
}

// FC head: out[b] = fc2_b + fc2_w . relu(fc1_b + fc1_w . h_T[b])
__global__ __launch_bounds__(256, 1)
void fc_head(const unsigned int* __restrict__ seqp,
             const float* __restrict__ fc1_w, const float* __restrict__ fc1_b,
             const float* __restrict__ fc2_w, const float* __restrict__ fc2_b,
             float* __restrict__ out)
{
    __shared__ float w1[FC1 * HDIM];
    __shared__ float b1[FC1];
    __shared__ float w2[FC1];
    const int tid = threadIdx.x;
    for (int i = tid; i < FC1 * HDIM; i += 256) w1[i] = fc1_w[i];
    if (tid < FC1) { b1[tid] = fc1_b[tid]; w2[tid] = fc2_w[tid]; }
    __syncthreads();

    const int b = blockIdx.x * 256 + tid;
    const size_t base = ((size_t)b * T_LEN + (T_LEN - 1)) * HDIM;
    float h[HDIM];
#pragma unroll
    for (int q = 0; q < HDIM; ++q) {
      unsigned int v = seqp[base + q];
      float hi = (float)__builtin_bit_cast(__bf16, (unsigned short)(v & 0xffffu));
      float lo = (float)__builtin_bit_cast(__bf16, (unsigned short)(v >> 16));
      h[q] = hi + lo;
    }
    float acc2 = fc2_b[0];
    for (int m = 0; m < FC1; ++m) {
      float a = b1[m];
#pragma unroll
      for (int q = 0; q < HDIM; ++q) a += w1[m * HDIM + q] * h[q];
      acc2 += w2[m] * fmaxf(a, 0.0f);
    }
    out[b] = acc2;
}

extern "C" void kernel_launch(void* const* d_in, const int* in_sizes, int n_in,
                              void* d_out, int out_size, void* d_ws, size_t ws_size,
                              hipStream_t stream) {
    const float* x         = (const float*)d_in[0];
    const float* w_ih0     = (const float*)d_in[1];
    const float* w_ih_rest = (const float*)d_in[2];
    const float* w_hh      = (const float*)d_in[3];
    const float* b_ih      = (const float*)d_in[4];
    const float* b_hh      = (const float*)d_in[5];
    const float* fc1_w     = (const float*)d_in[6];
    const float* fc1_b     = (const float*)d_in[7];
    const float* fc2_w     = (const float*)d_in[8];
    const float* fc2_b     = (const float*)d_in[9];
    float* out = (float*)d_out;

    unsigned int* seqp = (unsigned int*)d_ws;   // [B,T,64] packed = 256 MiB

    // layers 0+1 pipelined; writes seq1
    lstm_pair<0, true, false><<<dim3(B_TOT / 16), dim3(512), 0, stream>>>(
        x, w_ih0, w_ih_rest, w_hh, b_ih, b_hh, seqp);
    // layers 2+3 pipelined; reads seq1 / writes seq3 in-place (gap-3 trailing)
    lstm_pair<2, false, true><<<dim3(B_TOT / 16), dim3(512), 0, stream>>>(
        x, w_ih0, w_ih_rest, w_hh, b_ih, b_hh, seqp);
    // layer 4 (R9-proven producer/consumer), reads seq3 / writes seq4 in-place
    lstm_single<<<dim3(B_TOT / 16), dim3(512), 0, stream>>>(
        w_ih_rest + (size_t)3 * 256 * HDIM,
        w_hh + (size_t)4 * 256 * HDIM,
        b_ih + (size_t)4 * 256,
        b_hh + (size_t)4 * 256,
        seqp);
    fc_head<<<dim3(B_TOT / 256), dim3(256), 0, stream>>>(
        seqp, fc1_w, fc1_b, fc2_w, fc2_b, out);
}